// Round 5
// baseline (58.375 us; speedup 1.0000x reference)
//
#include <hip/hip_runtime.h>
#include <cfloat>
#include <cmath>

#define NB     4
#define NPTS   4096
#define NLAT   512
#define RPTS   16                 // i-points per thread
#define CJ     64                 // j-points per block
#define NJC    (NPTS / CJ)        // 64 j-chunks

// ---------------------------------------------------------------------------
// Prep: transform both point sets to (-2x, -2y, -2z, |p|^2) float4.
// grid = NB*NPTS/256 = 64 blocks.
// ---------------------------------------------------------------------------
__global__ __launch_bounds__(256) void k_prep(
    const float* __restrict__ pred_pos, const float* __restrict__ targ_pos,
    float4* __restrict__ predT, float4* __restrict__ targT)
{
    const int i = blockIdx.x * 256 + threadIdx.x;
    {
        const float x = pred_pos[3*i], y = pred_pos[3*i+1], z = pred_pos[3*i+2];
        predT[i] = make_float4(-2.f*x, -2.f*y, -2.f*z, fmaf(z,z,fmaf(y,y,x*x)));
    }
    {
        const float x = targ_pos[3*i], y = targ_pos[3*i+1], z = targ_pos[3*i+2];
        targT[i] = make_float4(-2.f*x, -2.f*y, -2.f*z, fmaf(z,z,fmaf(y,y,x*x)));
    }
}

// ---------------------------------------------------------------------------
// Kernel A: partial nearest-distance mins. grid = 3*NB*NJC = 768; block 256.
// No LDS: the j-points are wave-uniform -> uniform global reads promote to
// scalar loads (SMEM), leaving the vector pipe pure pair-math.
// Per j-pair per k: 6 fma + 1 min3 (3.5 ops/pair).
// Mode-2 self-skip: self occurs only at k_self = jc>>2 (block-uniform) for
// threads tid>>6 == jc&3 at j = tid&63 -> one extra fix chain, no per-pair
// compare in the 16 main chains.
// ---------------------------------------------------------------------------
__global__ __launch_bounds__(256) void k_min_dist(
    const float* __restrict__ pred_pos,
    const float* __restrict__ targ_pos,
    const float4* __restrict__ predT,
    const float4* __restrict__ targT,
    float* __restrict__ part_mins /* [3][NB][NJC][NPTS] */)
{
    const int tid  = threadIdx.x;
    const int jc   = blockIdx.x & (NJC - 1);
    const int b    = (blockIdx.x >> 6) & 3;
    const int mode = blockIdx.x >> 8;

    const float*  pb  = ((mode == 1) ? targ_pos : pred_pos) + (size_t)b * NPTS * 3;
    const float4* ob4 = ((mode == 0) ? targT : predT) + (size_t)b * NPTS + jc * CJ;

    float px[RPTS], py[RPTS], pz[RPTS], acc[RPTS];
    #pragma unroll
    for (int k = 0; k < RPTS; ++k) {
        const int i = tid + (k << 8);
        px[k] = pb[3*i]; py[k] = pb[3*i+1]; pz[k] = pb[3*i+2];
        acc[k] = FLT_MAX;
    }

    if (mode != 2) {
        #pragma unroll 2
        for (int j = 0; j < CJ; j += 2) {
            const float4 o1 = ob4[j];
            const float4 o2 = ob4[j + 1];
            #pragma unroll
            for (int k = 0; k < RPTS; ++k) {
                float t1 = fmaf(o1.x, px[k], o1.w);
                t1 = fmaf(o1.y, py[k], t1);
                t1 = fmaf(o1.z, pz[k], t1);
                float t2 = fmaf(o2.x, px[k], o2.w);
                t2 = fmaf(o2.y, py[k], t2);
                t2 = fmaf(o2.z, pz[k], t2);
                acc[k] = fminf(acc[k], fminf(t1, t2));   // -> v_min3_f32
            }
        }
    } else {
        const int  kself = jc >> 2;                // block-uniform
        const bool aff   = (tid >> 6) == (jc & 3);
        const int  jself = tid & 63;               // valid when aff
        float sx = 0.f, sy = 0.f, sz = 0.f;
        #pragma unroll
        for (int k = 0; k < RPTS; ++k) {
            sx = (k == kself) ? px[k] : sx;
            sy = (k == kself) ? py[k] : sy;
            sz = (k == kself) ? pz[k] : sz;
        }
        float accf = FLT_MAX;
        #pragma unroll 2
        for (int j = 0; j < CJ; j += 2) {
            const float4 o1 = ob4[j];
            const float4 o2 = ob4[j + 1];
            #pragma unroll
            for (int k = 0; k < RPTS; ++k) {
                float t1 = fmaf(o1.x, px[k], o1.w);
                t1 = fmaf(o1.y, py[k], t1);
                t1 = fmaf(o1.z, pz[k], t1);
                float t2 = fmaf(o2.x, px[k], o2.w);
                t2 = fmaf(o2.y, py[k], t2);
                t2 = fmaf(o2.z, pz[k], t2);
                acc[k] = fminf(acc[k], fminf(t1, t2));
            }
            float f1 = fmaf(o1.x, sx, o1.w);
            f1 = fmaf(o1.y, sy, f1);
            f1 = fmaf(o1.z, sz, f1);
            f1 = (j == jself) ? FLT_MAX : f1;
            float f2 = fmaf(o2.x, sx, o2.w);
            f2 = fmaf(o2.y, sy, f2);
            f2 = fmaf(o2.z, sz, f2);
            f2 = ((j + 1) == jself) ? FLT_MAX : f2;
            accf = fminf(accf, fminf(f1, f2));
        }
        #pragma unroll
        for (int k = 0; k < RPTS; ++k)
            acc[k] = (aff && k == kself) ? accf : acc[k];
    }

    float* mbase = part_mins + (((size_t)mode * NB + b) * NJC + jc) * NPTS;
    #pragma unroll
    for (int k = 0; k < RPTS; ++k) {
        const float p2 = fmaf(pz[k], pz[k], fmaf(py[k], py[k], px[k]*px[k]));
        mbase[tid + (k << 8)] = acc[k] + p2;    // coalesced per k
    }
}

// ---------------------------------------------------------------------------
__device__ __forceinline__ float block_sum(float v, float* red)
{
    #pragma unroll
    for (int o = 32; o >= 1; o >>= 1) v += __shfl_xor(v, o);
    const int w = threadIdx.x >> 6;
    __syncthreads();
    if ((threadIdx.x & 63) == 0) red[w] = v;
    __syncthreads();
    return red[0] + red[1] + red[2] + red[3];
}

// ---------------------------------------------------------------------------
// Fold: grid = 3*NB*16 = 192 blocks; block 256. Thread t owns one i-point,
// folds NJC partials (coalesced, stride NPTS), block-reduces sum & sumsq.
// ---------------------------------------------------------------------------
__global__ __launch_bounds__(256) void k_fold(
    const float* __restrict__ part_mins,
    float* __restrict__ sums /* [192] */, float* __restrict__ sumsqs /* [192] */)
{
    __shared__ float red[4];
    const int blk   = blockIdx.x;
    const int slice = blk & 15;
    const int b     = (blk >> 4) & 3;
    const int mode  = blk >> 6;
    const float* base = part_mins + ((size_t)mode * NB + b) * NJC * NPTS
                        + slice * 256 + threadIdx.x;
    float m = FLT_MAX;
    #pragma unroll 8
    for (int jc = 0; jc < NJC; ++jc)
        m = fminf(m, base[(size_t)jc * NPTS]);
    const float s  = block_sum(m, red);
    const float s2 = block_sum(m * m, red);
    if (threadIdx.x == 0) { sums[blk] = s; sumsqs[blk] = s2; }
}

// ---------------------------------------------------------------------------
// Finalize: KL + sizing MSE + combine. grid = 1, block = 256.
// ---------------------------------------------------------------------------
__global__ __launch_bounds__(256) void k_finalize(
    const float* __restrict__ pred_sizing,
    const float* __restrict__ targ_sizing,
    const float* __restrict__ mu,
    const float* __restrict__ logvar,
    const float* __restrict__ sums,
    const float* __restrict__ sumsqs,
    float* __restrict__ out)
{
    __shared__ float red[4];
    const int tid = threadIdx.x;

    float kls = 0.f;
    for (int i = tid; i < NB * NLAT; i += 256) {
        const float lv = logvar[i], m = mu[i];
        kls += 1.f + lv - m * m - expf(lv);
    }
    float szs = 0.f;
    #pragma unroll 4
    for (int i = tid; i < NB * NPTS; i += 256) {
        const float d = pred_sizing[i] - targ_sizing[i];
        szs += d * d;
    }
    kls = block_sum(kls, red);
    szs = block_sum(szs, red);

    if (tid == 0) {
        float cd_sum = 0.f, dens_sum = 0.f;
        for (int b = 0; b < NB; ++b) {
            float s01 = 0.f, sS = 0.f, sS2 = 0.f;
            for (int s = 0; s < 16; ++s) {
                s01 += sums[b * 16 + s] + sums[64 + b * 16 + s];
                sS  += sums[128 + b * 16 + s];
                sS2 += sumsqs[128 + b * 16 + s];
            }
            cd_sum += s01 / (float)NPTS;
            const float var = (sS2 - sS * sS / (float)NPTS) / (float)(NPTS - 1);
            dens_sum += sqrtf(fmaxf(var, 0.f));
        }
        const float cd     = cd_sum / (float)NB;
        const float dens   = dens_sum / (float)NB;
        const float kl     = -0.5f * kls / (float)(NB * NLAT);
        const float sizing = szs / (float)(NB * NPTS);
        out[0] = cd + 0.001f * kl + 0.1f * dens + 0.05f * sizing;
    }
}

// ---------------------------------------------------------------------------
extern "C" void kernel_launch(void* const* d_in, const int* in_sizes, int n_in,
                              void* d_out, int out_size, void* d_ws, size_t ws_size,
                              hipStream_t stream)
{
    const float* pred_pos    = (const float*)d_in[0];
    const float* pred_sizing = (const float*)d_in[1];
    const float* targ_pos    = (const float*)d_in[2];
    const float* targ_sizing = (const float*)d_in[3];
    const float* mu          = (const float*)d_in[4];
    const float* logvar      = (const float*)d_in[5];

    float4* predT = (float4*)d_ws;                               // 256 KiB
    float4* targT = predT + (size_t)NB * NPTS;                   // 256 KiB
    float*  part_mins = (float*)(targT + (size_t)NB * NPTS);     // 12.6 MiB
    float*  sums   = part_mins + (size_t)3 * NB * NJC * NPTS;    // 192
    float*  sumsqs = sums + 192;                                 // 192

    k_prep<<<dim3(NB * NPTS / 256), dim3(256), 0, stream>>>(
        pred_pos, targ_pos, predT, targT);
    k_min_dist<<<dim3(3 * NB * NJC), dim3(256), 0, stream>>>(
        pred_pos, targ_pos, predT, targT, part_mins);
    k_fold<<<dim3(192), dim3(256), 0, stream>>>(part_mins, sums, sumsqs);
    k_finalize<<<dim3(1), dim3(256), 0, stream>>>(
        pred_sizing, targ_sizing, mu, logvar, sums, sumsqs, (float*)d_out);
}

// Round 6
// 47.729 us; speedup vs baseline: 1.2230x; 1.2230x over previous
//
#include <hip/hip_runtime.h>
#include <cfloat>
#include <cmath>

#define NB     4
#define NPTS   4096
#define NLAT   512
#define RPTS   8                  // i-points per thread
#define CJ     64                 // j-points per block
#define NJC    (NPTS / CJ)        // 64 j-chunks
#define NIH    2                  // i-halves per (mode,b,jc)

// ---------------------------------------------------------------------------
// Prep: predT/targT = (-2x,-2y,-2z,|p|^2) for j-side; predR/targR =
// (x,y,z,|p|^2) for i-side. grid = NB*NPTS/256 = 64 blocks.
// ---------------------------------------------------------------------------
__global__ __launch_bounds__(256) void k_prep(
    const float* __restrict__ pred_pos, const float* __restrict__ targ_pos,
    float4* __restrict__ predT, float4* __restrict__ predR,
    float4* __restrict__ targT, float4* __restrict__ targR)
{
    const int i = blockIdx.x * 256 + threadIdx.x;
    {
        const float x = pred_pos[3*i], y = pred_pos[3*i+1], z = pred_pos[3*i+2];
        const float p2 = fmaf(z, z, fmaf(y, y, x * x));
        predT[i] = make_float4(-2.f*x, -2.f*y, -2.f*z, p2);
        predR[i] = make_float4(x, y, z, p2);
    }
    {
        const float x = targ_pos[3*i], y = targ_pos[3*i+1], z = targ_pos[3*i+2];
        const float p2 = fmaf(z, z, fmaf(y, y, x * x));
        targT[i] = make_float4(-2.f*x, -2.f*y, -2.f*z, p2);
        targR[i] = make_float4(x, y, z, p2);
    }
}

// ---------------------------------------------------------------------------
// Kernel A: partial nearest-distance mins. grid = 3*NB*NIH*NJC = 1536 blocks
// (6 waves/SIMD), block = 256. Each thread owns 8 i-points, scans 64 LDS-
// staged j-points in pairs: per pair-chain 6 fma + 1 min3. Mode-2 self-skip
// via one extra block-uniform fix chain (self at k_self=(jc&31)>>2 for
// threads tid>>6==jc&3, only in blocks with ihalf==jc>>5).
// Each (mode,b,jc,i) partial written exactly once -> deterministic.
// ---------------------------------------------------------------------------
__global__ __launch_bounds__(256) void k_min_dist(
    const float4* __restrict__ predT, const float4* __restrict__ predR,
    const float4* __restrict__ targT, const float4* __restrict__ targR,
    float* __restrict__ part_mins /* [3][NB][NJC][NPTS] */)
{
    __shared__ float4 lds[CJ];    // 1 KiB

    const int tid   = threadIdx.x;
    const int jc    = blockIdx.x & (NJC - 1);
    const int ihalf = (blockIdx.x >> 6) & 1;
    const int b     = (blockIdx.x >> 7) & 3;
    const int mode  = blockIdx.x >> 9;

    const float4* iR = ((mode == 1) ? targR : predR) + (size_t)b * NPTS;
    const float4* jT = ((mode == 0) ? targT : predT) + (size_t)b * NPTS + jc * CJ;

    if (tid < CJ) lds[tid] = jT[tid];

    float px[RPTS], py[RPTS], pz[RPTS], p2[RPTS], acc[RPTS];
    #pragma unroll
    for (int k = 0; k < RPTS; ++k) {
        const float4 r = iR[ihalf * 2048 + (k << 8) + tid];
        px[k] = r.x; py[k] = r.y; pz[k] = r.z; p2[k] = r.w;
        acc[k] = FLT_MAX;
    }
    __syncthreads();

    if (mode != 2) {
        #pragma unroll 2
        for (int j = 0; j < CJ; j += 2) {
            const float4 o1 = lds[j];
            const float4 o2 = lds[j + 1];
            #pragma unroll
            for (int k = 0; k < RPTS; ++k) {
                float t1 = fmaf(o1.x, px[k], o1.w);
                t1 = fmaf(o1.y, py[k], t1);
                t1 = fmaf(o1.z, pz[k], t1);
                float t2 = fmaf(o2.x, px[k], o2.w);
                t2 = fmaf(o2.y, py[k], t2);
                t2 = fmaf(o2.z, pz[k], t2);
                acc[k] = fminf(acc[k], fminf(t1, t2));   // -> v_min3_f32
            }
        }
    } else {
        const bool have = (jc >> 5) == ihalf;            // block-uniform
        const int  kself = (jc & 31) >> 2;               // block-uniform
        const bool aff   = have && ((tid >> 6) == (jc & 3));
        const int  jself = tid & 63;                     // valid when aff
        float sx = px[0], sy = py[0], sz = pz[0];
        #pragma unroll
        for (int k = 1; k < RPTS; ++k) {
            sx = (k == kself) ? px[k] : sx;
            sy = (k == kself) ? py[k] : sy;
            sz = (k == kself) ? pz[k] : sz;
        }
        float accf = FLT_MAX;
        #pragma unroll 2
        for (int j = 0; j < CJ; j += 2) {
            const float4 o1 = lds[j];
            const float4 o2 = lds[j + 1];
            #pragma unroll
            for (int k = 0; k < RPTS; ++k) {
                float t1 = fmaf(o1.x, px[k], o1.w);
                t1 = fmaf(o1.y, py[k], t1);
                t1 = fmaf(o1.z, pz[k], t1);
                float t2 = fmaf(o2.x, px[k], o2.w);
                t2 = fmaf(o2.y, py[k], t2);
                t2 = fmaf(o2.z, pz[k], t2);
                acc[k] = fminf(acc[k], fminf(t1, t2));
            }
            float f1 = fmaf(o1.x, sx, o1.w);
            f1 = fmaf(o1.y, sy, f1);
            f1 = fmaf(o1.z, sz, f1);
            f1 = (j == jself) ? FLT_MAX : f1;
            float f2 = fmaf(o2.x, sx, o2.w);
            f2 = fmaf(o2.y, sy, f2);
            f2 = fmaf(o2.z, sz, f2);
            f2 = ((j + 1) == jself) ? FLT_MAX : f2;
            accf = fminf(accf, fminf(f1, f2));
        }
        #pragma unroll
        for (int k = 0; k < RPTS; ++k)
            acc[k] = (aff && k == kself) ? accf : acc[k];
    }

    float* mb = part_mins + (((size_t)mode * NB + b) * NJC + jc) * NPTS
                + ihalf * 2048;
    #pragma unroll
    for (int k = 0; k < RPTS; ++k)
        mb[(k << 8) + tid] = acc[k] + p2[k];             // coalesced per k
}

// ---------------------------------------------------------------------------
__device__ __forceinline__ float block_sum(float v, float* red)
{
    #pragma unroll
    for (int o = 32; o >= 1; o >>= 1) v += __shfl_xor(v, o);
    const int w = threadIdx.x >> 6;
    __syncthreads();
    if ((threadIdx.x & 63) == 0) red[w] = v;
    __syncthreads();
    return red[0] + red[1] + red[2] + red[3];
}

// ---------------------------------------------------------------------------
// Fold: blocks 0..191 fold NJC partials per 256-i slice -> sum & sumsq
// (blk = mode*64 + b*16 + slice). Block 192: KL partial. Block 193: sizing
// partial. All deterministic fixed-order reductions.
// ---------------------------------------------------------------------------
__global__ __launch_bounds__(256) void k_fold(
    const float* __restrict__ part_mins,
    const float* __restrict__ pred_sizing,
    const float* __restrict__ targ_sizing,
    const float* __restrict__ mu,
    const float* __restrict__ logvar,
    float* __restrict__ sums /* [194] */,
    float* __restrict__ sumsqs /* [194] */)
{
    __shared__ float red[4];
    const int blk = blockIdx.x, tid = threadIdx.x;

    if (blk < 192) {
        const int slice = blk & 15;
        const int b     = (blk >> 4) & 3;
        const int mode  = blk >> 6;
        const float* base = part_mins + ((size_t)mode * NB + b) * NJC * NPTS
                            + slice * 256 + tid;
        float m = FLT_MAX;
        #pragma unroll 8
        for (int jc = 0; jc < NJC; ++jc)
            m = fminf(m, base[(size_t)jc * NPTS]);
        const float s  = block_sum(m, red);
        const float s2 = block_sum(m * m, red);
        if (tid == 0) { sums[blk] = s; sumsqs[blk] = s2; }
    } else if (blk == 192) {
        float kls = 0.f;
        for (int i = tid; i < NB * NLAT; i += 256) {
            const float lv = logvar[i], m = mu[i];
            kls += 1.f + lv - m * m - expf(lv);
        }
        kls = block_sum(kls, red);
        if (tid == 0) { sums[192] = kls; sumsqs[192] = 0.f; }
    } else {
        const float4* ps = (const float4*)pred_sizing;
        const float4* ts = (const float4*)targ_sizing;
        float szs = 0.f;
        #pragma unroll 4
        for (int i = tid; i < NB * NPTS / 4; i += 256) {
            const float4 a = ps[i], c = ts[i];
            const float d0 = a.x - c.x, d1 = a.y - c.y;
            const float d2 = a.z - c.z, d3 = a.w - c.w;
            szs += fmaf(d0, d0, fmaf(d1, d1, fmaf(d2, d2, d3 * d3)));
        }
        szs = block_sum(szs, red);
        if (tid == 0) { sums[193] = szs; sumsqs[193] = 0.f; }
    }
}

// ---------------------------------------------------------------------------
// Finalize: combine 194 scalars. grid = 1, block = 256.
// Group t>>4 = mode*4+b; 16-lane shuffle reduce stays within one wave.
// ---------------------------------------------------------------------------
__global__ __launch_bounds__(256) void k_finalize(
    const float* __restrict__ sums, const float* __restrict__ sumsqs,
    float* __restrict__ out)
{
    __shared__ float gs[12], gq[12];
    const int t = threadIdx.x;

    float v = 0.f, v2 = 0.f;
    if (t < 192) { v = sums[t]; v2 = sumsqs[t]; }
    #pragma unroll
    for (int o = 1; o < 16; o <<= 1) {
        v  += __shfl_xor(v,  o);
        v2 += __shfl_xor(v2, o);
    }
    if (t < 192 && (t & 15) == 0) { gs[t >> 4] = v; gq[t >> 4] = v2; }
    __syncthreads();

    if (t == 0) {
        float cd = 0.f, dens = 0.f;
        for (int b = 0; b < NB; ++b) {
            const float s01 = gs[b] + gs[4 + b];
            const float sS  = gs[8 + b];
            const float sS2 = gq[8 + b];
            cd += s01 / (float)NPTS;
            const float var = (sS2 - sS * sS / (float)NPTS) / (float)(NPTS - 1);
            dens += sqrtf(fmaxf(var, 0.f));
        }
        cd   /= (float)NB;
        dens /= (float)NB;
        const float kl     = -0.5f * sums[192] / (float)(NB * NLAT);
        const float sizing = sums[193] / (float)(NB * NPTS);
        out[0] = cd + 0.001f * kl + 0.1f * dens + 0.05f * sizing;
    }
}

// ---------------------------------------------------------------------------
extern "C" void kernel_launch(void* const* d_in, const int* in_sizes, int n_in,
                              void* d_out, int out_size, void* d_ws, size_t ws_size,
                              hipStream_t stream)
{
    const float* pred_pos    = (const float*)d_in[0];
    const float* pred_sizing = (const float*)d_in[1];
    const float* targ_pos    = (const float*)d_in[2];
    const float* targ_sizing = (const float*)d_in[3];
    const float* mu          = (const float*)d_in[4];
    const float* logvar      = (const float*)d_in[5];

    float4* predT = (float4*)d_ws;                               // 256 KiB
    float4* predR = predT + (size_t)NB * NPTS;
    float4* targT = predR + (size_t)NB * NPTS;
    float4* targR = targT + (size_t)NB * NPTS;
    float*  part_mins = (float*)(targR + (size_t)NB * NPTS);     // 12.6 MiB
    float*  sums   = part_mins + (size_t)3 * NB * NJC * NPTS;    // 194
    float*  sumsqs = sums + 194;                                 // 194

    k_prep<<<dim3(NB * NPTS / 256), dim3(256), 0, stream>>>(
        pred_pos, targ_pos, predT, predR, targT, targR);
    k_min_dist<<<dim3(3 * NB * NIH * NJC), dim3(256), 0, stream>>>(
        predT, predR, targT, targR, part_mins);
    k_fold<<<dim3(194), dim3(256), 0, stream>>>(
        part_mins, pred_sizing, targ_sizing, mu, logvar, sums, sumsqs);
    k_finalize<<<dim3(1), dim3(256), 0, stream>>>(sums, sumsqs, (float*)d_out);
}